// Round 1
// baseline (143.643 us; speedup 1.0000x reference)
//
#include <hip/hip_runtime.h>

#define TPB 256

// y is exactly 0.0f or 1.0f; -(y*log(p) + (1-y)*log1p(-p)) reduces to a select.
__device__ __forceinline__ float bce1(float p, float y) {
    return (y > 0.5f) ? -__logf(p) : -__logf(1.0f - p);
}

__global__ void __launch_bounds__(TPB) hml_main(
    const float* __restrict__ l1p,
    const float* __restrict__ l2pCC,
    const float* __restrict__ l2pURW,
    const float* __restrict__ p3a, const float* __restrict__ p3b,
    const float* __restrict__ p3c, const float* __restrict__ p3d,
    const float* __restrict__ p3e,
    const float* __restrict__ l1y,
    const float* __restrict__ l2yCC,
    const float* __restrict__ l2yURW,
    const float* __restrict__ y3a, const float* __restrict__ y3b,
    const float* __restrict__ y3c, const float* __restrict__ y3d,
    const float* __restrict__ y3e,
    int nrows, double* __restrict__ acc)
{
    double s1 = 0.0, s2cc = 0.0, s2urw = 0.0, s3 = 0.0;
    double nCC = 0.0, nURW = 0.0, n3 = 0.0;

    const int tid = blockIdx.x * blockDim.x + threadIdx.x;
    const int T   = gridDim.x * blockDim.x;

    // ---------- phase A: level1 + level2 (one row per thread, grid-stride) ----------
    for (int i = tid; i < nrows; i += T) {
        float2 p1 = ((const float2*)l1p)[i];
        float2 y1 = ((const float2*)l1y)[i];
        s1 += (double)(bce1(p1.x, y1.x) + bce1(p1.y, y1.y));

        bool aCC  = (y1.x > 0.5f);
        bool aURW = (y1.y > 0.5f);

        if (aCC) {
            nCC += 1.0;
            float s = 0.f;
            #pragma unroll
            for (int k = 0; k < 3; ++k)
                s += bce1(l2pCC[i * 3 + k], l2yCC[i * 3 + k]);
            s2cc += (double)s;
        }
        if (aURW) {
            nURW += 1.0;
            float2 p = ((const float2*)l2pURW)[i];
            float2 y = ((const float2*)l2yURW)[i];
            s2urw += (double)(bce1(p.x, y.x) + bce1(p.y, y.y));
        }
    }

    // ---------- phase B: 5 level3 arrays, flat float4 streams, mask-gated loads ----------
    const float* P3[5]  = { p3a, p3b, p3c, p3d, p3e };
    const float* Y3[5]  = { y3a, y3b, y3c, y3d, y3e };
    const float* L2Y[5] = { l2yCC, l2yCC, l2yCC, l2yURW, l2yURW };
    const int    BR[5]  = { 0, 0, 0, 1, 1 };
    const int    W[5]   = { 3, 3, 3, 2, 2 };
    const int    COL[5] = { 0, 1, 2, 0, 1 };

    const long nvec = (long)nrows * 8;   // 32 floats per row = 8 float4

    #pragma unroll
    for (int e = 0; e < 5; ++e) {
        const float4* p4  = (const float4*)P3[e];
        const float4* y4  = (const float4*)Y3[e];
        const float*  l2y = L2Y[e];
        const int br = BR[e], w = W[e], col = COL[e];

        for (long v = tid; v < nvec; v += T) {
            const int row = (int)(v >> 3);
            // mask: act_branch && (l2_label != 0). Label arrays are small and
            // cache-resident; payload (128 B/row) loads are skipped when masked.
            float a = l1y[row * 2 + br];
            if (a > 0.5f) {
                float l2v = l2y[row * w + col];
                if (l2v != 0.0f) {
                    float4 p = p4[v];
                    float4 y = y4[v];
                    float s = bce1(p.x, y.x) + bce1(p.y, y.y)
                            + bce1(p.z, y.z) + bce1(p.w, y.w);
                    s3 += (double)s;
                    if ((v & 7) == 0) n3 += 1.0;   // count each active row once
                }
            }
        }
    }

    // ---------- block reduction: 7 doubles ----------
    double vals[7] = { s1, s2cc, s2urw, s3, nCC, nURW, n3 };
    __shared__ double sm[4][7];
    const int lane = threadIdx.x & 63;
    const int wid  = threadIdx.x >> 6;

    #pragma unroll
    for (int j = 0; j < 7; ++j) {
        double v = vals[j];
        #pragma unroll
        for (int o = 32; o > 0; o >>= 1)
            v += __shfl_down(v, o, 64);
        if (lane == 0) sm[wid][j] = v;
    }
    __syncthreads();

    if (threadIdx.x == 0) {
        #pragma unroll
        for (int j = 0; j < 7; ++j) {
            double v = sm[0][j] + sm[1][j] + sm[2][j] + sm[3][j];
            atomicAdd(&acc[j], v);
        }
    }
}

__global__ void hml_final(const double* __restrict__ acc, float* __restrict__ out, int nrows)
{
    double s1 = acc[0], s2cc = acc[1], s2urw = acc[2], s3 = acc[3];
    double nCC = acc[4], nURW = acc[5], n3 = acc[6];

    double level1 = s1 / ((double)nrows * 2.0);

    double l2 = 0.0;
    if (nCC  > 0.0) l2 += s2cc  / (nCC  * 3.0);
    if (nURW > 0.0) l2 += s2urw / (nURW * 2.0);
    double level2 = 0.5 * l2;

    double level3 = (n3 > 0.0) ? (s3 / 32.0) / n3 : 0.0;

    out[0] = (float)(level1 + level2 + level3);
}

extern "C" void kernel_launch(void* const* d_in, const int* in_sizes, int n_in,
                              void* d_out, int out_size, void* d_ws, size_t ws_size,
                              hipStream_t stream) {
    const float* l1p   = (const float*)d_in[0];
    const float* l2pCC = (const float*)d_in[1];
    const float* l2pURW= (const float*)d_in[2];
    const float* p3a   = (const float*)d_in[3];
    const float* p3b   = (const float*)d_in[4];
    const float* p3c   = (const float*)d_in[5];
    const float* p3d   = (const float*)d_in[6];
    const float* p3e   = (const float*)d_in[7];
    const float* l1y   = (const float*)d_in[8];
    const float* l2yCC = (const float*)d_in[9];
    const float* l2yURW= (const float*)d_in[10];
    const float* y3a   = (const float*)d_in[11];
    const float* y3b   = (const float*)d_in[12];
    const float* y3c   = (const float*)d_in[13];
    const float* y3d   = (const float*)d_in[14];
    const float* y3e   = (const float*)d_in[15];

    const int nrows = in_sizes[0] / 2;

    double* acc = (double*)d_ws;
    hipMemsetAsync(acc, 0, 7 * sizeof(double), stream);

    int grid = (nrows + TPB - 1) / TPB;
    if (grid > 2048) grid = 2048;

    hml_main<<<grid, TPB, 0, stream>>>(
        l1p, l2pCC, l2pURW, p3a, p3b, p3c, p3d, p3e,
        l1y, l2yCC, l2yURW, y3a, y3b, y3c, y3d, y3e,
        nrows, acc);

    hml_final<<<1, 1, 0, stream>>>(acc, (float*)d_out, nrows);
}